// Round 10
// baseline (455.217 us; speedup 1.0000x reference)
//
#include <hip/hip_runtime.h>

#define N_NODES 100000
#define N_EDGES 640000
#define IN_DIM  128
#define OUT_DIM 128
#define N_REL   16
#define EPB     64
#define FNB     64                             // dst nodes per fused block
#define FB      ((N_NODES + FNB - 1) / FNB)    // 1563 fused blocks
#define N_SLOTS (N_EDGES + N_NODES)            // 740000 (edge + self slots)
#define SCAT_B  ((N_SLOTS + 255) / 256)        // 2891
#define NB_SCAN ((N_NODES + 255) / 256)        // 391
#define CVT_XB  (N_NODES * IN_DIM / 4 / 256)   // 12500 blocks for x
#define CVT_WB  (17 * 16384 / 256)             // 1088 blocks for W
#define HIST_B  ((N_EDGES + 255) / 256)        // 2500
#define CCAP    1024                           // real slots per sort chunk
#define SORD_SZ 1536                           // max padded (1024 + 17*31 -> mult of 32)
#define NWIN_MAX (SORD_SZ / 32)                // 48
#define PADE    0x07F00000u                    // pad entry: dstloc=127, src=0

typedef unsigned short u16;
typedef unsigned int   u32;
typedef unsigned long long u64;
typedef __attribute__((ext_vector_type(8))) short bf16x8;
typedef __attribute__((ext_vector_type(4))) float f32x4;

__device__ inline u16 f2bf(float f) {               // round-to-nearest-even
    u32 u = __builtin_bit_cast(u32, f);
    return (u16)((u + 0x7fffu + ((u >> 16) & 1u)) >> 16);
}
__device__ inline float bf2f(u16 s) {
    u32 u = ((u32)s) << 16;
    return __builtin_bit_cast(float, u);
}

// ---- fused pass 1: cvt-x, cvt-W (fragment layout), dst histogram ----
// W fragment layout per relation: u16 offset (c*4+kk)*512 + (q*16+n)*8 + j
// holds Wt[out=c*16+n][k=kk*32+q*8+j]  (lane==q*16+n -> stride-1 16B loads)
__global__ __launch_bounds__(256) void k_pre(const float* __restrict__ x,
                                             const float* __restrict__ rw,
                                             const float* __restrict__ sw,
                                             const int* __restrict__ dst,
                                             u16* __restrict__ xb,
                                             u16* __restrict__ wt,
                                             int* __restrict__ dst_count) {
    int b = blockIdx.x, t = threadIdx.x;
    if (b < CVT_XB) {
        int i = b * 256 + t;
        float4 v = ((const float4*)x)[i];
        ushort4 p; p.x = f2bf(v.x); p.y = f2bf(v.y); p.z = f2bf(v.z); p.w = f2bf(v.w);
        ((ushort4*)xb)[i] = p;
    } else if (b < CVT_XB + CVT_WB) {
        int i = (b - CVT_XB) * 256 + t;       // over 17*16384, exact
        int r = i >> 14, rem = i & 16383;
        int k = rem >> 7, np = rem & 127;     // input layout [r][k][n']
        float v = (r < 16) ? rw[i] : sw[rem];
        int c = np >> 4, nn = np & 15, kk = k >> 5, q = (k >> 3) & 3, j = k & 7;
        wt[(size_t)r * 16384 + (c * 4 + kk) * 512 + (q * 16 + nn) * 8 + j] = f2bf(v);
    } else {
        int e = (b - CVT_XB - CVT_WB) * 256 + t;
        if (e < N_EDGES) atomicAdd(&dst_count[dst[e]], 1);
    }
}

// ---------------- exclusive scan over (dst_count+1) -> row_ptr --------------
__global__ __launch_bounds__(256) void k_scan1(const int* __restrict__ dst_count,
                                               int* __restrict__ row_ptr,
                                               int* __restrict__ part) {
    __shared__ int buf[2][256];
    int t = threadIdx.x;
    int i = blockIdx.x * 256 + t;
    int v = (i < N_NODES) ? (dst_count[i] + 1) : 0;   // +1: self slot per node
    buf[0][t] = v;
    __syncthreads();
    int cur = 0;
    #pragma unroll
    for (int off = 1; off < 256; off <<= 1) {
        int nxt = cur ^ 1;
        int s = buf[cur][t];
        if (t >= off) s += buf[cur][t - off];
        buf[nxt][t] = s;
        __syncthreads();
        cur = nxt;
    }
    int inc = buf[cur][t];
    if (i < N_NODES) row_ptr[i] = inc - v;
    if (t == 255) part[blockIdx.x] = inc;
}

// single-block scan of the per-block partials (NB_SCAN=391 <= 512)
__global__ __launch_bounds__(512) void k_part(int* __restrict__ part) {
    __shared__ int buf[2][512];
    int t = threadIdx.x;
    int v = (t < NB_SCAN) ? part[t] : 0;
    buf[0][t] = v;
    __syncthreads();
    int cur = 0;
    #pragma unroll
    for (int off = 1; off < 512; off <<= 1) {
        int nxt = cur ^ 1;
        int s = buf[cur][t];
        if (t >= off) s += buf[cur][t - off];
        buf[nxt][t] = s;
        __syncthreads();
        cur = nxt;
    }
    int inc = buf[cur][t];
    if (t < NB_SCAN) part[t] = inc - v;
}

__global__ __launch_bounds__(256) void k_scan3(int* __restrict__ row_ptr,
                                               const int* __restrict__ part,
                                               int* __restrict__ cursor_dst) {
    int t = threadIdx.x;
    int i = blockIdx.x * 256 + t;
    if (i < N_NODES) {
        int r = row_ptr[i] + part[blockIdx.x];
        row_ptr[i] = r;
        cursor_dst[i] = r + 1;          // slot r is the self slot; edges at r+1
    }
    if (i == 0) row_ptr[N_NODES] = N_SLOTS;
}

// scatter (src, rel, dst) packed u64 into dst-sorted slots; self slots rel=16
__global__ __launch_bounds__(256) void k_scatter_dst(const int* __restrict__ src,
                                                     const int* __restrict__ dst,
                                                     const int* __restrict__ etype,
                                                     const int* __restrict__ row_ptr,
                                                     int* __restrict__ cursor_dst,
                                                     u64* __restrict__ pk) {
    int i = blockIdx.x * 256 + threadIdx.x;
    if (i < N_EDGES) {
        int d = dst[i];
        int p = atomicAdd(&cursor_dst[d], 1);
        pk[p] = (u64)(u32)src[i] | ((u64)(u32)etype[i] << 20) | ((u64)(u32)d << 32);
    } else if (i < N_SLOTS) {
        int nn = i - N_EDGES;
        pk[row_ptr[nn]] = (u64)(u32)nn | ((u64)16u << 20) | ((u64)(u32)nn << 32);
    }
}

// ---------------- fused: MFMA messages + MFMA segment-reduction -------------
// Block owns 64 dst nodes; slots (dst-sorted pk) counting-sorted by relation
// in LDS per 1024-chunk, rel runs padded to 32 (pad dstloc=127 -> S==0).
// Wave wv owns out-cols [wv*16, wv*16+16). Per 32-edge rel-uniform window:
//   stage 1: M[e][o] = sum_k x[e,k]*Wt[o,k]  (2x 16-edge tiles, 4 MFMA each;
//            operands SWAPPED vs msg kernel so edges land on D rows)
//   stage 2: acc2[dt] += S_dt * M   (S[d'][e] = dstloc[e]==dt*16+d', bf16 0/1)
// Accumulation lives entirely in the stage-2 MFMA C operand: no LDS atomics
// (r3's 94.7M-atomic death), no msgs round-trip (r9's 190MBx2 death).
__global__ __launch_bounds__(512, 4) void k_fused(const u16* __restrict__ xb,
                                                  const u16* __restrict__ wt,
                                                  const u64* __restrict__ pk,
                                                  const int* __restrict__ row_ptr,
                                                  const float* __restrict__ bias,
                                                  float* __restrict__ out) {
    __shared__ int s_bins[17];
    __shared__ int s_cur[17];
    __shared__ int s_npad;
    __shared__ int s_nwin;
    __shared__ unsigned char s_winrel[NWIN_MAX];
    __shared__ u32 s_ord[SORD_SZ];       // src | dstloc<<20

    int t = threadIdx.x;
    int n0 = blockIdx.x * FNB;
    int nend = min(n0 + FNB, N_NODES);
    int rows = nend - n0;
    int sb = row_ptr[n0], se = row_ptr[nend];

    int wv = t >> 6, lane = t & 63;
    int m = lane & 15, q = lane >> 4;

    f32x4 acc2[4] = {{0.f,0.f,0.f,0.f},{0.f,0.f,0.f,0.f},
                     {0.f,0.f,0.f,0.f},{0.f,0.f,0.f,0.f}};
    bf16x8 aw[4];                        // W frags for this wave's 16 cols
    int cur_rel = -1;

    for (int c0 = sb; c0 < se; c0 += CCAP) {
        int cnt = min(CCAP, se - c0);
        if (t < 17) s_bins[t] = 0;
        __syncthreads();                 // prev chunk compute done; bins clear
        u64 my0 = 0, my1 = 0;
        int k0 = -1, k1 = -1;
        if (t < cnt)       { my0 = pk[c0 + t];       k0 = (int)((my0 >> 20) & 31); atomicAdd(&s_bins[k0], 1); }
        if (t + 512 < cnt) { my1 = pk[c0 + t + 512]; k1 = (int)((my1 >> 20) & 31); atomicAdd(&s_bins[k1], 1); }
        __syncthreads();
        if (t == 0) {
            int s = 0, w = 0;
            for (int r = 0; r < 17; ++r) {
                s_cur[r] = s;
                int padded = (s_bins[r] + 31) & ~31;   // rel-uniform 32-windows
                for (int ww = 0; ww < (padded >> 5); ++ww)
                    s_winrel[w++] = (unsigned char)r;
                s += padded;
            }
            s_npad = s; s_nwin = w;
        }
        __syncthreads();
        int npad = s_npad;
        for (int i = t; i < npad; i += 512) s_ord[i] = PADE;
        __syncthreads();                 // pads in place before scatter
        if (k0 >= 0) {
            int p = atomicAdd(&s_cur[k0], 1);
            s_ord[p] = (u32)(my0 & 0xFFFFFu) | ((((u32)(my0 >> 32)) - (u32)n0) << 20);
        }
        if (k1 >= 0) {
            int p = atomicAdd(&s_cur[k1], 1);
            s_ord[p] = (u32)(my1 & 0xFFFFFu) | ((((u32)(my1 >> 32)) - (u32)n0) << 20);
        }
        __syncthreads();
        int nwin = s_nwin;
        for (int w = 0; w < nwin; ++w) {
            int rel = s_winrel[w];
            if (rel != cur_rel) {        // block-uniform; stride-1 16B L2 reads
                const bf16x8* wr = (const bf16x8*)(wt + (size_t)rel * 16384);
                #pragma unroll
                for (int kk = 0; kk < 4; ++kk)
                    aw[kk] = wr[(wv * 4 + kk) * 64 + lane];
                cur_rel = rel;
            }
            int wb = w * 32;
            // ---- stage 1: M for 2x16 edges, rows=edge cols=o (swapped ops)
            f32x4 t01[2];
            #pragma unroll
            for (int g = 0; g < 2; ++g) {
                u32 v = s_ord[wb + g * 16 + m];
                const u16* xrow = xb + (size_t)(v & 0xFFFFFu) * 128 + q * 8;
                bf16x8 bx[4];
                #pragma unroll
                for (int kk = 0; kk < 4; ++kk)
                    bx[kk] = *(const bf16x8*)(xrow + kk * 32);
                f32x4 acc = {0.f, 0.f, 0.f, 0.f};
                #pragma unroll
                for (int kk = 0; kk < 4; ++kk)
                    acc = __builtin_amdgcn_mfma_f32_16x16x32_bf16(bx[kk], aw[kk], acc, 0, 0, 0);
                t01[g] = acc;
            }
            // ---- dstloc of the window's 32 edges, 8 per lane (e = q*8+j)
            int dl[8];
            #pragma unroll
            for (int j = 0; j < 8; ++j)
                dl[j] = (int)(s_ord[wb + q * 8 + j] >> 20);
            // ---- B2: repack M (4 f32 rows/lane) into bf16 k-elems e=q*8+j
            int srcA = ((2 * q) & 3) * 16 + m;   // quartet source lanes
            int srcB = srcA + 16;
            int half = q >> 1;                   // 0: e<16 (tile0), 1: tile1
            u16 mb[8];
            #pragma unroll
            for (int r = 0; r < 4; ++r) {
                float a0 = __shfl(t01[0][r], srcA, 64);
                float a1 = __shfl(t01[1][r], srcA, 64);
                mb[r] = f2bf(half ? a1 : a0);
                float b0 = __shfl(t01[0][r], srcB, 64);
                float b1 = __shfl(t01[1][r], srcB, 64);
                mb[4 + r] = f2bf(half ? b1 : b0);
            }
            bf16x8 B2;
            #pragma unroll
            for (int j = 0; j < 8; ++j) B2[j] = (short)mb[j];
            // ---- stage 2: 4 d-tiles, accumulate in MFMA C operand
            #pragma unroll
            for (int dt = 0; dt < 4; ++dt) {
                int dval = dt * 16 + m;
                bf16x8 S;
                #pragma unroll
                for (int j = 0; j < 8; ++j)
                    S[j] = (short)((dl[j] == dval) ? (u16)0x3F80 : (u16)0);
                acc2[dt] = __builtin_amdgcn_mfma_f32_16x16x32_bf16(S, B2, acc2[dt], 0, 0, 0);
            }
        }
        __syncthreads();                 // all reads of s_ord done before reuse
    }
    // ---- epilogue: O[dt*16+q*4+r][wv*16+m], bias+relu, sequential-ish writes
    float bv = bias[wv * 16 + m];
    #pragma unroll
    for (int dt = 0; dt < 4; ++dt) {
        #pragma unroll
        for (int r = 0; r < 4; ++r) {
            int d = dt * 16 + q * 4 + r;
            if (d < rows)
                out[(size_t)(n0 + d) * 128 + wv * 16 + m] = fmaxf(acc2[dt][r] + bv, 0.f);
        }
    }
}

// ---------------- fallback (atomic path, small ws) ----------------
__global__ __launch_bounds__(128) void k_self_old(const float* __restrict__ x,
                                                  const float* __restrict__ sw,
                                                  const float* __restrict__ bias,
                                                  float* __restrict__ out) {
    __shared__ float s_x[8][IN_DIM];
    int t = threadIdx.x;
    int n0 = blockIdx.x * 8;
    for (int i = t; i < 8 * IN_DIM; i += 128) {
        int r = i >> 7, j = i & 127;
        s_x[r][j] = x[(size_t)(n0 + r) * IN_DIM + j];
    }
    __syncthreads();
    float acc[8] = {0.f,0.f,0.f,0.f,0.f,0.f,0.f,0.f};
    for (int k = 0; k < IN_DIM; ++k) {
        float w = sw[k * OUT_DIM + t];
        #pragma unroll
        for (int i = 0; i < 8; ++i) acc[i] += s_x[i][k] * w;
    }
    float b = bias[t];
    #pragma unroll
    for (int i = 0; i < 8; ++i)
        out[(size_t)(n0 + i) * OUT_DIM + t] = acc[i] + b;
}

__global__ __launch_bounds__(256) void k_hist_rel(const int* __restrict__ etype,
                                                  int* __restrict__ counts_rel) {
    __shared__ int bins[N_REL];
    int t = threadIdx.x;
    if (t < N_REL) bins[t] = 0;
    __syncthreads();
    int e = blockIdx.x * 256 + t;
    if (e < N_EDGES) atomicAdd(&bins[etype[e]], 1);
    __syncthreads();
    if (t < N_REL && bins[t]) atomicAdd(&counts_rel[t], bins[t]);
}

__global__ void k_scan_rel(const int* __restrict__ counts, int* __restrict__ cursor) {
    if (threadIdx.x == 0) {
        int s = 0;
        for (int r = 0; r < N_REL; ++r) { cursor[r] = s; s += counts[r]; }
    }
}

__global__ __launch_bounds__(256) void k_scatter_rel(const int* __restrict__ etype,
                                                     int* __restrict__ cursor,
                                                     int* __restrict__ sorted) {
    __shared__ int bins[N_REL];
    __shared__ int base[N_REL];
    int t = threadIdx.x;
    if (t < N_REL) bins[t] = 0;
    __syncthreads();
    int e = blockIdx.x * 256 + t;
    int rel = 0;
    bool valid = (e < N_EDGES);
    if (valid) { rel = etype[e]; atomicAdd(&bins[rel], 1); }
    __syncthreads();
    if (t < N_REL) {
        base[t] = bins[t] ? atomicAdd(&cursor[t], bins[t]) : 0;
        bins[t] = 0;
    }
    __syncthreads();
    if (valid) {
        int p = atomicAdd(&bins[rel], 1);
        sorted[base[rel] + p] = e;
    }
}

__global__ __launch_bounds__(256) void k_edge_atomic(const float* __restrict__ x,
                                              const float* __restrict__ rw,
                                              const int* __restrict__ src,
                                              const int* __restrict__ dst,
                                              const int* __restrict__ etype,
                                              const int* __restrict__ sorted,
                                              float* __restrict__ out) {
    __shared__ int s_src[EPB], s_dst[EPB], s_rel[EPB];
    __shared__ float s_x[EPB][IN_DIM];
    int t = threadIdx.x;
    int e0 = blockIdx.x * EPB;
    if (t < EPB) {
        int eid = sorted[e0 + t];
        s_src[t] = src[eid]; s_dst[t] = dst[eid]; s_rel[t] = etype[eid];
    }
    __syncthreads();
    for (int i = t; i < EPB * IN_DIM; i += 256) {
        int e = i >> 7, j = i & 127;
        s_x[e][j] = x[(size_t)s_src[e] * IN_DIM + j];
    }
    int rel0 = s_rel[0];
    bool uni = true;
    for (int i = 1; i < EPB; ++i) uni &= (s_rel[i] == rel0);
    __syncthreads();
    int cg = t & 31, eg = t >> 5;
    for (int i = 0; i < 8; ++i) {
        int e = eg * 8 + i;
        int rel = uni ? rel0 : s_rel[e];
        const float4* Wr = (const float4*)(rw + (size_t)rel * IN_DIM * OUT_DIM);
        float a0=0.f, a1=0.f, a2=0.f, a3=0.f;
        for (int k = 0; k < 128; ++k) {
            float4 w = Wr[k * 32 + cg];
            float xv = s_x[e][k];
            a0 += xv * w.x; a1 += xv * w.y; a2 += xv * w.z; a3 += xv * w.w;
        }
        float* o = out + (size_t)s_dst[e] * OUT_DIM + cg * 4;
        atomicAdd(o + 0, a0); atomicAdd(o + 1, a1);
        atomicAdd(o + 2, a2); atomicAdd(o + 3, a3);
    }
}

__global__ void k_relu(float* __restrict__ out) {
    int i = blockIdx.x * blockDim.x + threadIdx.x;
    float4* o4 = (float4*)out;
    const int n4 = N_NODES * OUT_DIM / 4;
    if (i < n4) {
        float4 v = o4[i];
        v.x = fmaxf(v.x, 0.f); v.y = fmaxf(v.y, 0.f);
        v.z = fmaxf(v.z, 0.f); v.w = fmaxf(v.w, 0.f);
        o4[i] = v;
    }
}

extern "C" void kernel_launch(void* const* d_in, const int* in_sizes, int n_in,
                              void* d_out, int out_size, void* d_ws, size_t ws_size,
                              hipStream_t stream) {
    const float* x     = (const float*)d_in[0];
    const int*   eidx  = (const int*)d_in[1];
    const int*   etype = (const int*)d_in[2];
    const float* rw    = (const float*)d_in[3];
    const float* sw    = (const float*)d_in[4];
    const float* bias  = (const float*)d_in[5];
    float* out = (float*)d_out;
    const int* src = eidx;
    const int* dst = eidx + N_EDGES;

    // ---- workspace layout ----
    int* part       = (int*)d_ws;                  // 512
    int* dst_count  = part + 512;                  // N
    int* row_ptr    = dst_count + N_NODES;         // N+1
    int* cursor_dst = row_ptr + N_NODES + 1;       // N
    size_t off0 = (((char*)(cursor_dst + N_NODES) - (char*)d_ws) + 255) & ~(size_t)255;
    u64* pk   = (u64*)((char*)d_ws + off0);        // N_SLOTS u64 (dst-sorted slots)
    u16* xb   = (u16*)(pk + N_SLOTS);              // N*128 bf16
    u16* wtb  = xb + (size_t)N_NODES * 128;        // 17*16384 bf16 (fragment order)
    size_t need = (size_t)((char*)(wtb + 17 * 16384) - (char*)d_ws);

    if (ws_size >= need) {
        hipMemsetAsync(dst_count, 0, (size_t)N_NODES * sizeof(int), stream);
        k_pre<<<CVT_XB + CVT_WB + HIST_B, 256, 0, stream>>>(
            x, rw, sw, dst, xb, wtb, dst_count);
        k_scan1<<<NB_SCAN, 256, 0, stream>>>(dst_count, row_ptr, part);
        k_part<<<1, 512, 0, stream>>>(part);
        k_scan3<<<NB_SCAN, 256, 0, stream>>>(row_ptr, part, cursor_dst);
        k_scatter_dst<<<SCAT_B, 256, 0, stream>>>(src, dst, etype, row_ptr,
                                                  cursor_dst, pk);
        k_fused<<<FB, 512, 0, stream>>>(xb, wtb, pk, row_ptr, bias, out);
    } else {
        // fallback: atomic path (needs only rel-sort scratch)
        int* counts_rel = (int*)d_ws;
        int* cursor_rel = counts_rel + 16;
        int* sortedf    = counts_rel + 64;
        hipMemsetAsync(counts_rel, 0, 16 * sizeof(int), stream);
        k_hist_rel<<<HIST_B, 256, 0, stream>>>(etype, counts_rel);
        k_scan_rel<<<1, 64, 0, stream>>>(counts_rel, cursor_rel);
        k_scatter_rel<<<HIST_B, 256, 0, stream>>>(etype, cursor_rel, sortedf);
        k_self_old<<<N_NODES / 8, 128, 0, stream>>>(x, sw, bias, out);
        k_edge_atomic<<<N_EDGES / EPB, 256, 0, stream>>>(x, rw, src, dst, etype, sortedf, out);
        k_relu<<<(N_NODES * OUT_DIM / 4 + 255) / 256, 256, 0, stream>>>(out);
    }
}

// Round 11
// 424.317 us; speedup vs baseline: 1.0728x; 1.0728x over previous
//
#include <hip/hip_runtime.h>

#define N_NODES 100000
#define N_EDGES 640000
#define IN_DIM  128
#define OUT_DIM 128
#define N_REL   16
#define EPB     64
#define FNB     64                             // dst nodes per fused block
#define FB      ((N_NODES + FNB - 1) / FNB)    // 1563 fused blocks
#define N_SLOTS (N_EDGES + N_NODES)            // 740000 (edge + self slots)
#define SCAT_B  ((N_SLOTS + 255) / 256)        // 2891
#define NB_SCAN ((N_NODES + 255) / 256)        // 391
#define CVT_XB  (N_NODES * IN_DIM / 4 / 256)   // 12500 blocks for x
#define CVT_WB  (17 * 16384 / 256)             // 1088 blocks for W
#define HIST_B  ((N_EDGES + 255) / 256)        // 2500
#define CCAP    1024                           // real slots per sort chunk
#define SORD_SZ 1568                           // >= 1024 + 17*31 = 1551
#define NWIN_MAX 56                            // >= 49 worst-case windows
#define PADE    0x07F00000u                    // pad entry: dstloc=127, src=0

#if defined(__has_builtin)
#if __has_builtin(__builtin_amdgcn_mfma_f32_16x16x16bf16_1k)
#define HAVE_MFMA16 1
#endif
#endif

typedef unsigned short u16;
typedef unsigned int   u32;
typedef unsigned long long u64;
typedef __attribute__((ext_vector_type(8))) short bf16x8;
typedef __attribute__((ext_vector_type(4))) short bf16x4;
typedef __attribute__((ext_vector_type(4))) float f32x4;

__device__ inline u16 f2bf(float f) {               // round-to-nearest-even
    u32 u = __builtin_bit_cast(u32, f);
    return (u16)((u + 0x7fffu + ((u >> 16) & 1u)) >> 16);
}
__device__ inline float bf2f(u16 s) {
    u32 u = ((u32)s) << 16;
    return __builtin_bit_cast(float, u);
}

// ---- fused pass 1: cvt-x, cvt-W (fragment layout), dst histogram ----
// W fragment layout per relation: u16 offset (c*4+kk)*512 + (q*16+n)*8 + j
// holds Wt[out=c*16+n][k=kk*32+q*8+j]  (lane==q*16+n -> stride-1 16B loads)
__global__ __launch_bounds__(256) void k_pre(const float* __restrict__ x,
                                             const float* __restrict__ rw,
                                             const float* __restrict__ sw,
                                             const int* __restrict__ dst,
                                             u16* __restrict__ xb,
                                             u16* __restrict__ wt,
                                             int* __restrict__ dst_count) {
    int b = blockIdx.x, t = threadIdx.x;
    if (b < CVT_XB) {
        int i = b * 256 + t;
        float4 v = ((const float4*)x)[i];
        ushort4 p; p.x = f2bf(v.x); p.y = f2bf(v.y); p.z = f2bf(v.z); p.w = f2bf(v.w);
        ((ushort4*)xb)[i] = p;
    } else if (b < CVT_XB + CVT_WB) {
        int i = (b - CVT_XB) * 256 + t;       // over 17*16384, exact
        int r = i >> 14, rem = i & 16383;
        int k = rem >> 7, np = rem & 127;     // input layout [r][k][n']
        float v = (r < 16) ? rw[i] : sw[rem];
        int c = np >> 4, nn = np & 15, kk = k >> 5, q = (k >> 3) & 3, j = k & 7;
        wt[(size_t)r * 16384 + (c * 4 + kk) * 512 + (q * 16 + nn) * 8 + j] = f2bf(v);
    } else {
        int e = (b - CVT_XB - CVT_WB) * 256 + t;
        if (e < N_EDGES) atomicAdd(&dst_count[dst[e]], 1);
    }
}

// ---------------- exclusive scan over (dst_count+1) -> row_ptr --------------
__global__ __launch_bounds__(256) void k_scan1(const int* __restrict__ dst_count,
                                               int* __restrict__ row_ptr,
                                               int* __restrict__ part) {
    __shared__ int buf[2][256];
    int t = threadIdx.x;
    int i = blockIdx.x * 256 + t;
    int v = (i < N_NODES) ? (dst_count[i] + 1) : 0;   // +1: self slot per node
    buf[0][t] = v;
    __syncthreads();
    int cur = 0;
    #pragma unroll
    for (int off = 1; off < 256; off <<= 1) {
        int nxt = cur ^ 1;
        int s = buf[cur][t];
        if (t >= off) s += buf[cur][t - off];
        buf[nxt][t] = s;
        __syncthreads();
        cur = nxt;
    }
    int inc = buf[cur][t];
    if (i < N_NODES) row_ptr[i] = inc - v;
    if (t == 255) part[blockIdx.x] = inc;
}

// single-block scan of the per-block partials (NB_SCAN=391 <= 512)
__global__ __launch_bounds__(512) void k_part(int* __restrict__ part) {
    __shared__ int buf[2][512];
    int t = threadIdx.x;
    int v = (t < NB_SCAN) ? part[t] : 0;
    buf[0][t] = v;
    __syncthreads();
    int cur = 0;
    #pragma unroll
    for (int off = 1; off < 512; off <<= 1) {
        int nxt = cur ^ 1;
        int s = buf[cur][t];
        if (t >= off) s += buf[cur][t - off];
        buf[nxt][t] = s;
        __syncthreads();
        cur = nxt;
    }
    int inc = buf[cur][t];
    if (t < NB_SCAN) part[t] = inc - v;
}

__global__ __launch_bounds__(256) void k_scan3(int* __restrict__ row_ptr,
                                               const int* __restrict__ part,
                                               int* __restrict__ cursor_dst) {
    int t = threadIdx.x;
    int i = blockIdx.x * 256 + t;
    if (i < N_NODES) {
        int r = row_ptr[i] + part[blockIdx.x];
        row_ptr[i] = r;
        cursor_dst[i] = r + 1;          // slot r is the self slot; edges at r+1
    }
    if (i == 0) row_ptr[N_NODES] = N_SLOTS;
}

// scatter (src, rel, dst) packed u64 into dst-sorted slots; self slots rel=16
__global__ __launch_bounds__(256) void k_scatter_dst(const int* __restrict__ src,
                                                     const int* __restrict__ dst,
                                                     const int* __restrict__ etype,
                                                     const int* __restrict__ row_ptr,
                                                     int* __restrict__ cursor_dst,
                                                     u64* __restrict__ pk) {
    int i = blockIdx.x * 256 + threadIdx.x;
    if (i < N_EDGES) {
        int d = dst[i];
        int p = atomicAdd(&cursor_dst[d], 1);
        pk[p] = (u64)(u32)src[i] | ((u64)(u32)etype[i] << 20) | ((u64)(u32)d << 32);
    } else if (i < N_SLOTS) {
        int nn = i - N_EDGES;
        pk[row_ptr[nn]] = (u64)(u32)nn | ((u64)16u << 20) | ((u64)(u32)nn << 32);
    }
}

// ---------------- fused: MFMA messages + MFMA segment-reduction -------------
// Block owns 64 dst nodes; slots (dst-sorted pk) counting-sorted by relation
// in LDS per 1024-chunk, rel runs padded to 32 (pad dstloc=127 -> S==0).
// Wave wv owns out-cols [wv*16, wv*16+16). Per 32-edge rel-uniform window:
//   stage 1 (K=32, 2x16-edge tiles): M[e][o], D frag = M[e=q*4+r][o=wv*16+m]
//   stage 2 (K=16, r11): B-operand of 16x16x16 wants B[k=q*4+j][col=m] ==
//     EXACTLY stage-1's D frag in-lane -> B2[j]=f2bf(t01[g][j]), no shuffles.
//     S[m][e]=(dl[e]==dt*16+m) from one ds_read_b128 of 4 packed dstlocs.
//   r10's 16-shfl repack = 8.06M bank conflicts + serial chain -> deleted.
__global__ __launch_bounds__(512, 4) void k_fused(const u16* __restrict__ xb,
                                                  const u16* __restrict__ wt,
                                                  const u64* __restrict__ pk,
                                                  const int* __restrict__ row_ptr,
                                                  const float* __restrict__ bias,
                                                  float* __restrict__ out) {
    __shared__ int s_bins[17];
    __shared__ int s_cur[17];
    __shared__ int s_npad;
    __shared__ int s_nwin;
    __shared__ unsigned char s_winrel[NWIN_MAX];
    __shared__ u32 s_ord[SORD_SZ];       // src | dstloc<<20

    int t = threadIdx.x;
    int n0 = blockIdx.x * FNB;
    int nend = min(n0 + FNB, N_NODES);
    int rows = nend - n0;
    int sb = row_ptr[n0], se = row_ptr[nend];

    int wv = t >> 6, lane = t & 63;
    int m = lane & 15, q = lane >> 4;

    f32x4 acc2[4] = {{0.f,0.f,0.f,0.f},{0.f,0.f,0.f,0.f},
                     {0.f,0.f,0.f,0.f},{0.f,0.f,0.f,0.f}};
    bf16x8 aw[4];                        // W frags for this wave's 16 cols
    int cur_rel = -1;

    for (int c0 = sb; c0 < se; c0 += CCAP) {
        int cnt = min(CCAP, se - c0);
        if (t < 17) s_bins[t] = 0;
        __syncthreads();                 // prev chunk compute done; bins clear
        u64 my0 = 0, my1 = 0;
        int k0 = -1, k1 = -1;
        if (t < cnt)       { my0 = pk[c0 + t];       k0 = (int)((my0 >> 20) & 31); atomicAdd(&s_bins[k0], 1); }
        if (t + 512 < cnt) { my1 = pk[c0 + t + 512]; k1 = (int)((my1 >> 20) & 31); atomicAdd(&s_bins[k1], 1); }
        __syncthreads();
        if (t == 0) {
            int s = 0, w = 0;
            for (int r = 0; r < 17; ++r) {
                s_cur[r] = s;
                int padded = (s_bins[r] + 31) & ~31;   // rel-uniform 32-windows
                for (int ww = 0; ww < (padded >> 5); ++ww)
                    s_winrel[w++] = (unsigned char)r;
                s += padded;
            }
            s_npad = s; s_nwin = w;
        }
        __syncthreads();
        int npad = s_npad;
        for (int i = t; i < npad; i += 512) s_ord[i] = PADE;
        __syncthreads();                 // pads in place before scatter
        if (k0 >= 0) {
            int p = atomicAdd(&s_cur[k0], 1);
            s_ord[p] = (u32)(my0 & 0xFFFFFu) | ((((u32)(my0 >> 32)) - (u32)n0) << 20);
        }
        if (k1 >= 0) {
            int p = atomicAdd(&s_cur[k1], 1);
            s_ord[p] = (u32)(my1 & 0xFFFFFu) | ((((u32)(my1 >> 32)) - (u32)n0) << 20);
        }
        __syncthreads();
        int nwin = s_nwin;
        for (int w = 0; w < nwin; ++w) {
            int rel = s_winrel[w];
            if (rel != cur_rel) {        // block-uniform; stride-1 16B L2 reads
                const bf16x8* wr = (const bf16x8*)(wt + (size_t)rel * 16384);
                #pragma unroll
                for (int kk = 0; kk < 4; ++kk)
                    aw[kk] = wr[(wv * 4 + kk) * 64 + lane];
                cur_rel = rel;
            }
            int wb = w * 32;
            // ---- stage 1: load both tiles' x frags first (ILP), then MFMA
            bf16x8 bx[2][4];
            #pragma unroll
            for (int g = 0; g < 2; ++g) {
                u32 v = s_ord[wb + g * 16 + m];
                const u16* xrow = xb + (size_t)(v & 0xFFFFFu) * 128 + q * 8;
                #pragma unroll
                for (int kk = 0; kk < 4; ++kk)
                    bx[g][kk] = *(const bf16x8*)(xrow + kk * 32);
            }
            f32x4 t01[2];
            #pragma unroll
            for (int g = 0; g < 2; ++g) {
                f32x4 acc = {0.f, 0.f, 0.f, 0.f};
                #pragma unroll
                for (int kk = 0; kk < 4; ++kk)
                    acc = __builtin_amdgcn_mfma_f32_16x16x32_bf16(bx[g][kk], aw[kk], acc, 0, 0, 0);
                t01[g] = acc;
            }
#ifdef HAVE_MFMA16
            // ---- stage 2 (K=16, in-lane): per tile g, B2 = f2bf(t01[g])
            #pragma unroll
            for (int g = 0; g < 2; ++g) {
                uint4 dlv = *(const uint4*)&s_ord[wb + g * 16 + q * 4];  // bcast
                int d0 = (int)(dlv.x >> 20), d1 = (int)(dlv.y >> 20);
                int d2 = (int)(dlv.z >> 20), d3 = (int)(dlv.w >> 20);
                bf16x4 B2;
                B2[0] = (short)f2bf(t01[g][0]); B2[1] = (short)f2bf(t01[g][1]);
                B2[2] = (short)f2bf(t01[g][2]); B2[3] = (short)f2bf(t01[g][3]);
                #pragma unroll
                for (int dt = 0; dt < 4; ++dt) {
                    int dval = dt * 16 + m;
                    bf16x4 S;
                    S[0] = (short)((d0 == dval) ? (u16)0x3F80 : (u16)0);
                    S[1] = (short)((d1 == dval) ? (u16)0x3F80 : (u16)0);
                    S[2] = (short)((d2 == dval) ? (u16)0x3F80 : (u16)0);
                    S[3] = (short)((d3 == dval) ? (u16)0x3F80 : (u16)0);
                    acc2[dt] = __builtin_amdgcn_mfma_f32_16x16x16bf16_1k(S, B2, acc2[dt], 0, 0, 0);
                }
            }
#else
            // ---- fallback: r10 shfl repack + K=32 stage 2 (proven correct)
            int dl[8];
            #pragma unroll
            for (int j = 0; j < 8; ++j)
                dl[j] = (int)(s_ord[wb + q * 8 + j] >> 20);
            int srcA = ((2 * q) & 3) * 16 + m;
            int srcB = srcA + 16;
            int half = q >> 1;
            u16 mb[8];
            #pragma unroll
            for (int r = 0; r < 4; ++r) {
                float a0 = __shfl(t01[0][r], srcA, 64);
                float a1 = __shfl(t01[1][r], srcA, 64);
                mb[r] = f2bf(half ? a1 : a0);
                float b0 = __shfl(t01[0][r], srcB, 64);
                float b1 = __shfl(t01[1][r], srcB, 64);
                mb[4 + r] = f2bf(half ? b1 : b0);
            }
            bf16x8 B2;
            #pragma unroll
            for (int j = 0; j < 8; ++j) B2[j] = (short)mb[j];
            #pragma unroll
            for (int dt = 0; dt < 4; ++dt) {
                int dval = dt * 16 + m;
                bf16x8 S;
                #pragma unroll
                for (int j = 0; j < 8; ++j)
                    S[j] = (short)((dl[j] == dval) ? (u16)0x3F80 : (u16)0);
                acc2[dt] = __builtin_amdgcn_mfma_f32_16x16x32_bf16(S, B2, acc2[dt], 0, 0, 0);
            }
#endif
        }
        __syncthreads();                 // all reads of s_ord done before reuse
    }
    // ---- epilogue: O[dt*16+q*4+r][wv*16+m], bias+relu
    float bv = bias[wv * 16 + m];
    #pragma unroll
    for (int dt = 0; dt < 4; ++dt) {
        #pragma unroll
        for (int r = 0; r < 4; ++r) {
            int d = dt * 16 + q * 4 + r;
            if (d < rows)
                out[(size_t)(n0 + d) * 128 + wv * 16 + m] = fmaxf(acc2[dt][r] + bv, 0.f);
        }
    }
}

// ---------------- fallback (atomic path, small ws) ----------------
__global__ __launch_bounds__(128) void k_self_old(const float* __restrict__ x,
                                                  const float* __restrict__ sw,
                                                  const float* __restrict__ bias,
                                                  float* __restrict__ out) {
    __shared__ float s_x[8][IN_DIM];
    int t = threadIdx.x;
    int n0 = blockIdx.x * 8;
    for (int i = t; i < 8 * IN_DIM; i += 128) {
        int r = i >> 7, j = i & 127;
        s_x[r][j] = x[(size_t)(n0 + r) * IN_DIM + j];
    }
    __syncthreads();
    float acc[8] = {0.f,0.f,0.f,0.f,0.f,0.f,0.f,0.f};
    for (int k = 0; k < IN_DIM; ++k) {
        float w = sw[k * OUT_DIM + t];
        #pragma unroll
        for (int i = 0; i < 8; ++i) acc[i] += s_x[i][k] * w;
    }
    float b = bias[t];
    #pragma unroll
    for (int i = 0; i < 8; ++i)
        out[(size_t)(n0 + i) * OUT_DIM + t] = acc[i] + b;
}

__global__ __launch_bounds__(256) void k_hist_rel(const int* __restrict__ etype,
                                                  int* __restrict__ counts_rel) {
    __shared__ int bins[N_REL];
    int t = threadIdx.x;
    if (t < N_REL) bins[t] = 0;
    __syncthreads();
    int e = blockIdx.x * 256 + t;
    if (e < N_EDGES) atomicAdd(&bins[etype[e]], 1);
    __syncthreads();
    if (t < N_REL && bins[t]) atomicAdd(&counts_rel[t], bins[t]);
}

__global__ void k_scan_rel(const int* __restrict__ counts, int* __restrict__ cursor) {
    if (threadIdx.x == 0) {
        int s = 0;
        for (int r = 0; r < N_REL; ++r) { cursor[r] = s; s += counts[r]; }
    }
}

__global__ __launch_bounds__(256) void k_scatter_rel(const int* __restrict__ etype,
                                                     int* __restrict__ cursor,
                                                     int* __restrict__ sorted) {
    __shared__ int bins[N_REL];
    __shared__ int base[N_REL];
    int t = threadIdx.x;
    if (t < N_REL) bins[t] = 0;
    __syncthreads();
    int e = blockIdx.x * 256 + t;
    int rel = 0;
    bool valid = (e < N_EDGES);
    if (valid) { rel = etype[e]; atomicAdd(&bins[rel], 1); }
    __syncthreads();
    if (t < N_REL) {
        base[t] = bins[t] ? atomicAdd(&cursor[t], bins[t]) : 0;
        bins[t] = 0;
    }
    __syncthreads();
    if (valid) {
        int p = atomicAdd(&bins[rel], 1);
        sorted[base[rel] + p] = e;
    }
}

__global__ __launch_bounds__(256) void k_edge_atomic(const float* __restrict__ x,
                                              const float* __restrict__ rw,
                                              const int* __restrict__ src,
                                              const int* __restrict__ dst,
                                              const int* __restrict__ etype,
                                              const int* __restrict__ sorted,
                                              float* __restrict__ out) {
    __shared__ int s_src[EPB], s_dst[EPB], s_rel[EPB];
    __shared__ float s_x[EPB][IN_DIM];
    int t = threadIdx.x;
    int e0 = blockIdx.x * EPB;
    if (t < EPB) {
        int eid = sorted[e0 + t];
        s_src[t] = src[eid]; s_dst[t] = dst[eid]; s_rel[t] = etype[eid];
    }
    __syncthreads();
    for (int i = t; i < EPB * IN_DIM; i += 256) {
        int e = i >> 7, j = i & 127;
        s_x[e][j] = x[(size_t)s_src[e] * IN_DIM + j];
    }
    int rel0 = s_rel[0];
    bool uni = true;
    for (int i = 1; i < EPB; ++i) uni &= (s_rel[i] == rel0);
    __syncthreads();
    int cg = t & 31, eg = t >> 5;
    for (int i = 0; i < 8; ++i) {
        int e = eg * 8 + i;
        int rel = uni ? rel0 : s_rel[e];
        const float4* Wr = (const float4*)(rw + (size_t)rel * IN_DIM * OUT_DIM);
        float a0=0.f, a1=0.f, a2=0.f, a3=0.f;
        for (int k = 0; k < 128; ++k) {
            float4 w = Wr[k * 32 + cg];
            float xv = s_x[e][k];
            a0 += xv * w.x; a1 += xv * w.y; a2 += xv * w.z; a3 += xv * w.w;
        }
        float* o = out + (size_t)s_dst[e] * OUT_DIM + cg * 4;
        atomicAdd(o + 0, a0); atomicAdd(o + 1, a1);
        atomicAdd(o + 2, a2); atomicAdd(o + 3, a3);
    }
}

__global__ void k_relu(float* __restrict__ out) {
    int i = blockIdx.x * blockDim.x + threadIdx.x;
    float4* o4 = (float4*)out;
    const int n4 = N_NODES * OUT_DIM / 4;
    if (i < n4) {
        float4 v = o4[i];
        v.x = fmaxf(v.x, 0.f); v.y = fmaxf(v.y, 0.f);
        v.z = fmaxf(v.z, 0.f); v.w = fmaxf(v.w, 0.f);
        o4[i] = v;
    }
}

extern "C" void kernel_launch(void* const* d_in, const int* in_sizes, int n_in,
                              void* d_out, int out_size, void* d_ws, size_t ws_size,
                              hipStream_t stream) {
    const float* x     = (const float*)d_in[0];
    const int*   eidx  = (const int*)d_in[1];
    const int*   etype = (const int*)d_in[2];
    const float* rw    = (const float*)d_in[3];
    const float* sw    = (const float*)d_in[4];
    const float* bias  = (const float*)d_in[5];
    float* out = (float*)d_out;
    const int* src = eidx;
    const int* dst = eidx + N_EDGES;

    // ---- workspace layout ----
    int* part       = (int*)d_ws;                  // 512
    int* dst_count  = part + 512;                  // N
    int* row_ptr    = dst_count + N_NODES;         // N+1
    int* cursor_dst = row_ptr + N_NODES + 1;       // N
    size_t off0 = (((char*)(cursor_dst + N_NODES) - (char*)d_ws) + 255) & ~(size_t)255;
    u64* pk   = (u64*)((char*)d_ws + off0);        // N_SLOTS u64 (dst-sorted slots)
    u16* xb   = (u16*)(pk + N_SLOTS);              // N*128 bf16
    u16* wtb  = xb + (size_t)N_NODES * 128;        // 17*16384 bf16 (fragment order)
    size_t need = (size_t)((char*)(wtb + 17 * 16384) - (char*)d_ws);

    if (ws_size >= need) {
        hipMemsetAsync(dst_count, 0, (size_t)N_NODES * sizeof(int), stream);
        k_pre<<<CVT_XB + CVT_WB + HIST_B, 256, 0, stream>>>(
            x, rw, sw, dst, xb, wtb, dst_count);
        k_scan1<<<NB_SCAN, 256, 0, stream>>>(dst_count, row_ptr, part);
        k_part<<<1, 512, 0, stream>>>(part);
        k_scan3<<<NB_SCAN, 256, 0, stream>>>(row_ptr, part, cursor_dst);
        k_scatter_dst<<<SCAT_B, 256, 0, stream>>>(src, dst, etype, row_ptr,
                                                  cursor_dst, pk);
        k_fused<<<FB, 512, 0, stream>>>(xb, wtb, pk, row_ptr, bias, out);
    } else {
        // fallback: atomic path (needs only rel-sort scratch)
        int* counts_rel = (int*)d_ws;
        int* cursor_rel = counts_rel + 16;
        int* sortedf    = counts_rel + 64;
        hipMemsetAsync(counts_rel, 0, 16 * sizeof(int), stream);
        k_hist_rel<<<HIST_B, 256, 0, stream>>>(etype, counts_rel);
        k_scan_rel<<<1, 64, 0, stream>>>(counts_rel, cursor_rel);
        k_scatter_rel<<<HIST_B, 256, 0, stream>>>(etype, cursor_rel, sortedf);
        k_self_old<<<N_NODES / 8, 128, 0, stream>>>(x, sw, bias, out);
        k_edge_atomic<<<N_EDGES / EPB, 256, 0, stream>>>(x, rw, src, dst, etype, sortedf, out);
        k_relu<<<(N_NODES * OUT_DIM / 4 + 255) / 256, 256, 0, stream>>>(out);
    }
}

// Round 12
// 417.453 us; speedup vs baseline: 1.0905x; 1.0164x over previous
//
#include <hip/hip_runtime.h>

#define N_NODES 100000
#define N_EDGES 640000
#define IN_DIM  128
#define OUT_DIM 128
#define N_REL   16
#define EPB     64
#define FNB     64                             // dst nodes per fused block
#define FB      ((N_NODES + FNB - 1) / FNB)    // 1563 fused blocks
#define N_SLOTS (N_EDGES + N_NODES)            // 740000 (edge + self slots)
#define SCAT_B  ((N_SLOTS + 255) / 256)        // 2891
#define NB_SCAN ((N_NODES + 255) / 256)        // 391
#define CVT_XB  (N_NODES * IN_DIM / 4 / 256)   // 12500 blocks for x
#define CVT_WB  (17 * 16384 / 256)             // 1088 blocks for W
#define HIST_B  ((N_EDGES + 255) / 256)        // 2500
#define CCAP    1024                           // real slots per sort chunk
#define SORD_SZ 1280                           // >= 1024 + 17*15 = 1279
#define NWIN_MAX 80                            // 1280/16
#define PADE    0x07F00000u                    // pad entry: dstloc=127, src=0

typedef unsigned short u16;
typedef unsigned int   u32;
typedef unsigned long long u64;
typedef __attribute__((ext_vector_type(8))) short bf16x8;
typedef __attribute__((ext_vector_type(4))) short bf16x4;
typedef __attribute__((ext_vector_type(4))) float f32x4;

__device__ inline u16 f2bf(float f) {               // round-to-nearest-even
    u32 u = __builtin_bit_cast(u32, f);
    return (u16)((u + 0x7fffu + ((u >> 16) & 1u)) >> 16);
}
__device__ inline float bf2f(u16 s) {
    u32 u = ((u32)s) << 16;
    return __builtin_bit_cast(float, u);
}

// ---- fused pass 1: cvt-x, cvt-W (fragment layout), dst histogram ----
// W fragment layout per relation: u16 offset (c*4+kk)*512 + (q*16+n)*8 + j
// holds Wt[out=c*16+n][k=kk*32+q*8+j]  (lane==q*16+n -> stride-1 16B loads)
__global__ __launch_bounds__(256) void k_pre(const float* __restrict__ x,
                                             const float* __restrict__ rw,
                                             const float* __restrict__ sw,
                                             const int* __restrict__ dst,
                                             u16* __restrict__ xb,
                                             u16* __restrict__ wt,
                                             int* __restrict__ dst_count) {
    int b = blockIdx.x, t = threadIdx.x;
    if (b < CVT_XB) {
        int i = b * 256 + t;
        float4 v = ((const float4*)x)[i];
        ushort4 p; p.x = f2bf(v.x); p.y = f2bf(v.y); p.z = f2bf(v.z); p.w = f2bf(v.w);
        ((ushort4*)xb)[i] = p;
    } else if (b < CVT_XB + CVT_WB) {
        int i = (b - CVT_XB) * 256 + t;       // over 17*16384, exact
        int r = i >> 14, rem = i & 16383;
        int k = rem >> 7, np = rem & 127;     // input layout [r][k][n']
        float v = (r < 16) ? rw[i] : sw[rem];
        int c = np >> 4, nn = np & 15, kk = k >> 5, q = (k >> 3) & 3, j = k & 7;
        wt[(size_t)r * 16384 + (c * 4 + kk) * 512 + (q * 16 + nn) * 8 + j] = f2bf(v);
    } else {
        int e = (b - CVT_XB - CVT_WB) * 256 + t;
        if (e < N_EDGES) atomicAdd(&dst_count[dst[e]], 1);
    }
}

// ---------------- exclusive scan over (dst_count+1) -> row_ptr --------------
__global__ __launch_bounds__(256) void k_scan1(const int* __restrict__ dst_count,
                                               int* __restrict__ row_ptr,
                                               int* __restrict__ part) {
    __shared__ int buf[2][256];
    int t = threadIdx.x;
    int i = blockIdx.x * 256 + t;
    int v = (i < N_NODES) ? (dst_count[i] + 1) : 0;   // +1: self slot per node
    buf[0][t] = v;
    __syncthreads();
    int cur = 0;
    #pragma unroll
    for (int off = 1; off < 256; off <<= 1) {
        int nxt = cur ^ 1;
        int s = buf[cur][t];
        if (t >= off) s += buf[cur][t - off];
        buf[nxt][t] = s;
        __syncthreads();
        cur = nxt;
    }
    int inc = buf[cur][t];
    if (i < N_NODES) row_ptr[i] = inc - v;
    if (t == 255) part[blockIdx.x] = inc;
}

// single-block scan of the per-block partials (NB_SCAN=391 <= 512)
__global__ __launch_bounds__(512) void k_part(int* __restrict__ part) {
    __shared__ int buf[2][512];
    int t = threadIdx.x;
    int v = (t < NB_SCAN) ? part[t] : 0;
    buf[0][t] = v;
    __syncthreads();
    int cur = 0;
    #pragma unroll
    for (int off = 1; off < 512; off <<= 1) {
        int nxt = cur ^ 1;
        int s = buf[cur][t];
        if (t >= off) s += buf[cur][t - off];
        buf[nxt][t] = s;
        __syncthreads();
        cur = nxt;
    }
    int inc = buf[cur][t];
    if (t < NB_SCAN) part[t] = inc - v;
}

__global__ __launch_bounds__(256) void k_scan3(int* __restrict__ row_ptr,
                                               const int* __restrict__ part,
                                               int* __restrict__ cursor_dst) {
    int t = threadIdx.x;
    int i = blockIdx.x * 256 + t;
    if (i < N_NODES) {
        int r = row_ptr[i] + part[blockIdx.x];
        row_ptr[i] = r;
        cursor_dst[i] = r + 1;          // slot r is the self slot; edges at r+1
    }
    if (i == 0) row_ptr[N_NODES] = N_SLOTS;
}

// scatter (src, rel, dst) packed u64 into dst-sorted slots; self slots rel=16
__global__ __launch_bounds__(256) void k_scatter_dst(const int* __restrict__ src,
                                                     const int* __restrict__ dst,
                                                     const int* __restrict__ etype,
                                                     const int* __restrict__ row_ptr,
                                                     int* __restrict__ cursor_dst,
                                                     u64* __restrict__ pk) {
    int i = blockIdx.x * 256 + threadIdx.x;
    if (i < N_EDGES) {
        int d = dst[i];
        int p = atomicAdd(&cursor_dst[d], 1);
        pk[p] = (u64)(u32)src[i] | ((u64)(u32)etype[i] << 20) | ((u64)(u32)d << 32);
    } else if (i < N_SLOTS) {
        int nn = i - N_EDGES;
        pk[row_ptr[nn]] = (u64)(u32)nn | ((u64)16u << 20) | ((u64)(u32)nn << 32);
    }
}

// ---------------- fused: MFMA messages + MFMA segment-reduction -------------
// Block owns 64 dst nodes; slots (dst-sorted pk) counting-sorted by relation
// in LDS per 1024-chunk; rel runs padded to 16 (r12: was 32 -> ~400K pad
// slots, 35% overhead; 16 halves it). Window = one 16-edge tile.
// Wave wv owns out-cols [wv*16, wv*16+16). Per window:
//   stage 1 (K=32): M[e][o], D frag = M[e=q*4+r][o=wv*16+m]
//   stage 2 (K=16, in-lane): B2[j]=f2bf(t01[j]); S[m][e]=(dl[e]==dt*16+m)
// r12: 2x-unrolled DOUBLE-BUFFER PREFETCH (bxA/bxB named reg sets) — window
// w+1's four scattered x-loads issue before window w's MFMAs; vmcnt is
// in-order so stage-1's wait on current frags leaves next-window loads in
// flight. Hides the ~500cy L2/L3 gather under 8 MFMAs + S-build.
__global__ __launch_bounds__(512, 4) void k_fused(const u16* __restrict__ xb,
                                                  const u16* __restrict__ wt,
                                                  const u64* __restrict__ pk,
                                                  const int* __restrict__ row_ptr,
                                                  const float* __restrict__ bias,
                                                  float* __restrict__ out) {
    __shared__ int s_bins[17];
    __shared__ int s_cur[17];
    __shared__ int s_npad;
    __shared__ int s_nwin;
    __shared__ unsigned char s_winrel[NWIN_MAX];
    __shared__ u32 s_ord[SORD_SZ];       // src | dstloc<<20

    int t = threadIdx.x;
    int n0 = blockIdx.x * FNB;
    int nend = min(n0 + FNB, N_NODES);
    int rows = nend - n0;
    int sb = row_ptr[n0], se = row_ptr[nend];

    int wv = t >> 6, lane = t & 63;
    int m = lane & 15, q = lane >> 4;

    f32x4 acc2[4] = {{0.f,0.f,0.f,0.f},{0.f,0.f,0.f,0.f},
                     {0.f,0.f,0.f,0.f},{0.f,0.f,0.f,0.f}};
    bf16x8 aw[4];                        // W frags for this wave's 16 cols
    int cur_rel = -1;

    bf16x8 bxA0, bxA1, bxA2, bxA3;       // double-buffered x fragments
    bf16x8 bxB0, bxB1, bxB2, bxB3;       // (named: no dynamic-index scratch)

#define ISSUE(P0, P1, P2, P3, WB) {                                          \
    u32 v_ = s_ord[(WB) + m];                                                \
    const u16* xr_ = xb + (size_t)(v_ & 0xFFFFFu) * 128 + q * 8;             \
    P0 = *(const bf16x8*)(xr_);        P1 = *(const bf16x8*)(xr_ + 32);      \
    P2 = *(const bf16x8*)(xr_ + 64);   P3 = *(const bf16x8*)(xr_ + 96); }

#define COMPUTE(P0, P1, P2, P3, W) {                                         \
    int rel_ = s_winrel[W];                                                  \
    if (rel_ != cur_rel) {                                                   \
        const bf16x8* wr_ = (const bf16x8*)(wt + (size_t)rel_ * 16384);      \
        aw[0] = wr_[(wv * 4 + 0) * 64 + lane];                               \
        aw[1] = wr_[(wv * 4 + 1) * 64 + lane];                               \
        aw[2] = wr_[(wv * 4 + 2) * 64 + lane];                               \
        aw[3] = wr_[(wv * 4 + 3) * 64 + lane];                               \
        cur_rel = rel_;                                                      \
    }                                                                        \
    int wb_ = (W) * 16;                                                      \
    f32x4 t01 = {0.f, 0.f, 0.f, 0.f};                                        \
    t01 = __builtin_amdgcn_mfma_f32_16x16x32_bf16(P0, aw[0], t01, 0, 0, 0);  \
    t01 = __builtin_amdgcn_mfma_f32_16x16x32_bf16(P1, aw[1], t01, 0, 0, 0);  \
    t01 = __builtin_amdgcn_mfma_f32_16x16x32_bf16(P2, aw[2], t01, 0, 0, 0);  \
    t01 = __builtin_amdgcn_mfma_f32_16x16x32_bf16(P3, aw[3], t01, 0, 0, 0);  \
    uint4 dlv_ = *(const uint4*)&s_ord[wb_ + q * 4];                         \
    int d0_ = (int)(dlv_.x >> 20), d1_ = (int)(dlv_.y >> 20);                \
    int d2_ = (int)(dlv_.z >> 20), d3_ = (int)(dlv_.w >> 20);                \
    bf16x4 B2_;                                                              \
    B2_[0] = (short)f2bf(t01[0]); B2_[1] = (short)f2bf(t01[1]);              \
    B2_[2] = (short)f2bf(t01[2]); B2_[3] = (short)f2bf(t01[3]);              \
    _Pragma("unroll")                                                        \
    for (int dt = 0; dt < 4; ++dt) {                                         \
        int dval_ = dt * 16 + m;                                             \
        bf16x4 S_;                                                           \
        S_[0] = (short)((d0_ == dval_) ? (u16)0x3F80 : (u16)0);              \
        S_[1] = (short)((d1_ == dval_) ? (u16)0x3F80 : (u16)0);              \
        S_[2] = (short)((d2_ == dval_) ? (u16)0x3F80 : (u16)0);              \
        S_[3] = (short)((d3_ == dval_) ? (u16)0x3F80 : (u16)0);              \
        acc2[dt] = __builtin_amdgcn_mfma_f32_16x16x16bf16_1k(S_, B2_, acc2[dt], 0, 0, 0); \
    } }

    for (int c0 = sb; c0 < se; c0 += CCAP) {
        int cnt = min(CCAP, se - c0);
        if (t < 17) s_bins[t] = 0;
        __syncthreads();                 // prev chunk compute done; bins clear
        u64 my0 = 0, my1 = 0;
        int k0 = -1, k1 = -1;
        if (t < cnt)       { my0 = pk[c0 + t];       k0 = (int)((my0 >> 20) & 31); atomicAdd(&s_bins[k0], 1); }
        if (t + 512 < cnt) { my1 = pk[c0 + t + 512]; k1 = (int)((my1 >> 20) & 31); atomicAdd(&s_bins[k1], 1); }
        __syncthreads();
        if (t == 0) {
            int s = 0, w = 0;
            for (int r = 0; r < 17; ++r) {
                s_cur[r] = s;
                int padded = (s_bins[r] + 15) & ~15;   // 16-edge windows
                for (int ww = 0; ww < (padded >> 4); ++ww)
                    s_winrel[w++] = (unsigned char)r;
                s += padded;
            }
            s_npad = s; s_nwin = w;
        }
        __syncthreads();
        int npad = s_npad;
        for (int i = t; i < npad; i += 512) s_ord[i] = PADE;
        __syncthreads();                 // pads in place before scatter
        if (k0 >= 0) {
            int p = atomicAdd(&s_cur[k0], 1);
            s_ord[p] = (u32)(my0 & 0xFFFFFu) | ((((u32)(my0 >> 32)) - (u32)n0) << 20);
        }
        if (k1 >= 0) {
            int p = atomicAdd(&s_cur[k1], 1);
            s_ord[p] = (u32)(my1 & 0xFFFFFu) | ((((u32)(my1 >> 32)) - (u32)n0) << 20);
        }
        __syncthreads();
        int nwin = s_nwin;
        if (nwin > 0) ISSUE(bxA0, bxA1, bxA2, bxA3, 0);
        for (int w = 0; w < nwin; w += 2) {
            if (w + 1 < nwin) ISSUE(bxB0, bxB1, bxB2, bxB3, (w + 1) * 16);
            COMPUTE(bxA0, bxA1, bxA2, bxA3, w);
            if (w + 2 < nwin) ISSUE(bxA0, bxA1, bxA2, bxA3, (w + 2) * 16);
            if (w + 1 < nwin) COMPUTE(bxB0, bxB1, bxB2, bxB3, w + 1);
        }
        __syncthreads();                 // all reads of s_ord done before reuse
    }
#undef ISSUE
#undef COMPUTE
    // ---- epilogue: O[dt*16+q*4+r][wv*16+m], bias+relu
    float bv = bias[wv * 16 + m];
    #pragma unroll
    for (int dt = 0; dt < 4; ++dt) {
        #pragma unroll
        for (int r = 0; r < 4; ++r) {
            int d = dt * 16 + q * 4 + r;
            if (d < rows)
                out[(size_t)(n0 + d) * 128 + wv * 16 + m] = fmaxf(acc2[dt][r] + bv, 0.f);
        }
    }
}

// ---------------- fallback (atomic path, small ws) ----------------
__global__ __launch_bounds__(128) void k_self_old(const float* __restrict__ x,
                                                  const float* __restrict__ sw,
                                                  const float* __restrict__ bias,
                                                  float* __restrict__ out) {
    __shared__ float s_x[8][IN_DIM];
    int t = threadIdx.x;
    int n0 = blockIdx.x * 8;
    for (int i = t; i < 8 * IN_DIM; i += 128) {
        int r = i >> 7, j = i & 127;
        s_x[r][j] = x[(size_t)(n0 + r) * IN_DIM + j];
    }
    __syncthreads();
    float acc[8] = {0.f,0.f,0.f,0.f,0.f,0.f,0.f,0.f};
    for (int k = 0; k < IN_DIM; ++k) {
        float w = sw[k * OUT_DIM + t];
        #pragma unroll
        for (int i = 0; i < 8; ++i) acc[i] += s_x[i][k] * w;
    }
    float b = bias[t];
    #pragma unroll
    for (int i = 0; i < 8; ++i)
        out[(size_t)(n0 + i) * OUT_DIM + t] = acc[i] + b;
}

__global__ __launch_bounds__(256) void k_hist_rel(const int* __restrict__ etype,
                                                  int* __restrict__ counts_rel) {
    __shared__ int bins[N_REL];
    int t = threadIdx.x;
    if (t < N_REL) bins[t] = 0;
    __syncthreads();
    int e = blockIdx.x * 256 + t;
    if (e < N_EDGES) atomicAdd(&bins[etype[e]], 1);
    __syncthreads();
    if (t < N_REL && bins[t]) atomicAdd(&counts_rel[t], bins[t]);
}

__global__ void k_scan_rel(const int* __restrict__ counts, int* __restrict__ cursor) {
    if (threadIdx.x == 0) {
        int s = 0;
        for (int r = 0; r < N_REL; ++r) { cursor[r] = s; s += counts[r]; }
    }
}

__global__ __launch_bounds__(256) void k_scatter_rel(const int* __restrict__ etype,
                                                     int* __restrict__ cursor,
                                                     int* __restrict__ sorted) {
    __shared__ int bins[N_REL];
    __shared__ int base[N_REL];
    int t = threadIdx.x;
    if (t < N_REL) bins[t] = 0;
    __syncthreads();
    int e = blockIdx.x * 256 + t;
    int rel = 0;
    bool valid = (e < N_EDGES);
    if (valid) { rel = etype[e]; atomicAdd(&bins[rel], 1); }
    __syncthreads();
    if (t < N_REL) {
        base[t] = bins[t] ? atomicAdd(&cursor[t], bins[t]) : 0;
        bins[t] = 0;
    }
    __syncthreads();
    if (valid) {
        int p = atomicAdd(&bins[rel], 1);
        sorted[base[rel] + p] = e;
    }
}

__global__ __launch_bounds__(256) void k_edge_atomic(const float* __restrict__ x,
                                              const float* __restrict__ rw,
                                              const int* __restrict__ src,
                                              const int* __restrict__ dst,
                                              const int* __restrict__ etype,
                                              const int* __restrict__ sorted,
                                              float* __restrict__ out) {
    __shared__ int s_src[EPB], s_dst[EPB], s_rel[EPB];
    __shared__ float s_x[EPB][IN_DIM];
    int t = threadIdx.x;
    int e0 = blockIdx.x * EPB;
    if (t < EPB) {
        int eid = sorted[e0 + t];
        s_src[t] = src[eid]; s_dst[t] = dst[eid]; s_rel[t] = etype[eid];
    }
    __syncthreads();
    for (int i = t; i < EPB * IN_DIM; i += 256) {
        int e = i >> 7, j = i & 127;
        s_x[e][j] = x[(size_t)s_src[e] * IN_DIM + j];
    }
    int rel0 = s_rel[0];
    bool uni = true;
    for (int i = 1; i < EPB; ++i) uni &= (s_rel[i] == rel0);
    __syncthreads();
    int cg = t & 31, eg = t >> 5;
    for (int i = 0; i < 8; ++i) {
        int e = eg * 8 + i;
        int rel = uni ? rel0 : s_rel[e];
        const float4* Wr = (const float4*)(rw + (size_t)rel * IN_DIM * OUT_DIM);
        float a0=0.f, a1=0.f, a2=0.f, a3=0.f;
        for (int k = 0; k < 128; ++k) {
            float4 w = Wr[k * 32 + cg];
            float xv = s_x[e][k];
            a0 += xv * w.x; a1 += xv * w.y; a2 += xv * w.z; a3 += xv * w.w;
        }
        float* o = out + (size_t)s_dst[e] * OUT_DIM + cg * 4;
        atomicAdd(o + 0, a0); atomicAdd(o + 1, a1);
        atomicAdd(o + 2, a2); atomicAdd(o + 3, a3);
    }
}

__global__ void k_relu(float* __restrict__ out) {
    int i = blockIdx.x * blockDim.x + threadIdx.x;
    float4* o4 = (float4*)out;
    const int n4 = N_NODES * OUT_DIM / 4;
    if (i < n4) {
        float4 v = o4[i];
        v.x = fmaxf(v.x, 0.f); v.y = fmaxf(v.y, 0.f);
        v.z = fmaxf(v.z, 0.f); v.w = fmaxf(v.w, 0.f);
        o4[i] = v;
    }
}

extern "C" void kernel_launch(void* const* d_in, const int* in_sizes, int n_in,
                              void* d_out, int out_size, void* d_ws, size_t ws_size,
                              hipStream_t stream) {
    const float* x     = (const float*)d_in[0];
    const int*   eidx  = (const int*)d_in[1];
    const int*   etype = (const int*)d_in[2];
    const float* rw    = (const float*)d_in[3];
    const float* sw    = (const float*)d_in[4];
    const float* bias  = (const float*)d_in[5];
    float* out = (float*)d_out;
    const int* src = eidx;
    const int* dst = eidx + N_EDGES;

    // ---- workspace layout ----
    int* part       = (int*)d_ws;                  // 512
    int* dst_count  = part + 512;                  // N
    int* row_ptr    = dst_count + N_NODES;         // N+1
    int* cursor_dst = row_ptr + N_NODES + 1;       // N
    size_t off0 = (((char*)(cursor_dst + N_NODES) - (char*)d_ws) + 255) & ~(size_t)255;
    u64* pk   = (u64*)((char*)d_ws + off0);        // N_SLOTS u64 (dst-sorted slots)
    u16* xb   = (u16*)(pk + N_SLOTS);              // N*128 bf16
    u16* wtb  = xb + (size_t)N_NODES * 128;        // 17*16384 bf16 (fragment order)
    size_t need = (size_t)((char*)(wtb + 17 * 16384) - (char*)d_ws);

    if (ws_size >= need) {
        hipMemsetAsync(dst_count, 0, (size_t)N_NODES * sizeof(int), stream);
        k_pre<<<CVT_XB + CVT_WB + HIST_B, 256, 0, stream>>>(
            x, rw, sw, dst, xb, wtb, dst_count);
        k_scan1<<<NB_SCAN, 256, 0, stream>>>(dst_count, row_ptr, part);
        k_part<<<1, 512, 0, stream>>>(part);
        k_scan3<<<NB_SCAN, 256, 0, stream>>>(row_ptr, part, cursor_dst);
        k_scatter_dst<<<SCAT_B, 256, 0, stream>>>(src, dst, etype, row_ptr,
                                                  cursor_dst, pk);
        k_fused<<<FB, 512, 0, stream>>>(xb, wtb, pk, row_ptr, bias, out);
    } else {
        // fallback: atomic path (needs only rel-sort scratch)
        int* counts_rel = (int*)d_ws;
        int* cursor_rel = counts_rel + 16;
        int* sortedf    = counts_rel + 64;
        hipMemsetAsync(counts_rel, 0, 16 * sizeof(int), stream);
        k_hist_rel<<<HIST_B, 256, 0, stream>>>(etype, counts_rel);
        k_scan_rel<<<1, 64, 0, stream>>>(counts_rel, cursor_rel);
        k_scatter_rel<<<HIST_B, 256, 0, stream>>>(etype, cursor_rel, sortedf);
        k_self_old<<<N_NODES / 8, 128, 0, stream>>>(x, sw, bias, out);
        k_edge_atomic<<<N_EDGES / EPB, 256, 0, stream>>>(x, rw, src, dst, etype, sortedf, out);
        k_relu<<<(N_NODES * OUT_DIM / 4 + 255) / 256, 256, 0, stream>>>(out);
    }
}